// Round 2
// baseline (337.314 us; speedup 1.0000x reference)
//
#include <hip/hip_runtime.h>
#include <math.h>

#define N_SEQ 1152
#define T_LEN 16
#define DM    256
#define DI    512
#define HWSZ  576

// ---------------------------------------------------------------------------
// K1: xz = x @ in_proj_w^T.  64n x 256e tile, 8x8 microtile per thread.
// Per kk: 64 FMA vs 4 ds_read_b128 -> LDS pipe ~balanced with VALU.
// xc_raw (all t, e<512); z_raw (t==15 only, e>=512).
// ---------------------------------------------------------------------------
__global__ __launch_bounds__(256) void k1_inproj(const float* __restrict__ x_seq,
                                                 const float* __restrict__ w,      // (1024,256)
                                                 float* __restrict__ xc_raw,       // [16][1152][512]
                                                 float* __restrict__ z_raw)        // [1152][512]
{
    const int t  = blockIdx.z;
    const int by = blockIdx.y;
    if (t != 15 && by >= 2) return;   // z half only needed at last step
    const int n0 = blockIdx.x * 64;
    const int e0 = by * 256;
    const int b  = n0 / HWSZ;
    const int hw0 = n0 - b * HWSZ;
    const int tid = threadIdx.x;
    const int tx = tid & 31;   // e-group: e = e0 + tx*4 + 128*j
    const int ty = tid >> 5;   // n-group: n = n0 + ty*8 + i

    __shared__ float a_tile[16][68];    // [c][n], padded
    __shared__ float b_tile[16][260];   // [c][e], padded

    float acc[8][8] = {};  // [n][e]

    const float* xbase = x_seq + (size_t)b * (T_LEN * DM * HWSZ) + (size_t)t * (DM * HWSZ);

    for (int k0 = 0; k0 < DM; k0 += 16) {
        {   // A: 16c x 64n, n-contiguous float4 loads
            int cl = tid >> 4;            // 0..15
            int n4 = (tid & 15) * 4;      // 0..60
            float4 v = *(const float4*)(xbase + (size_t)(k0 + cl) * HWSZ + hw0 + n4);
            *(float4*)&a_tile[cl][n4] = v;
        }
        {   // B: 256e x 16c, transposed into LDS; one e-row per thread
            const float* wr = &w[(size_t)(e0 + tid) * DM + k0];
#pragma unroll
            for (int c4 = 0; c4 < 16; c4 += 4) {
                float4 v = *(const float4*)(wr + c4);
                b_tile[c4 + 0][tid] = v.x;
                b_tile[c4 + 1][tid] = v.y;
                b_tile[c4 + 2][tid] = v.z;
                b_tile[c4 + 3][tid] = v.w;
            }
        }
        __syncthreads();
#pragma unroll
        for (int kk = 0; kk < 16; ++kk) {
            float4 a0 = *(const float4*)&a_tile[kk][ty * 8];
            float4 a1 = *(const float4*)&a_tile[kk][ty * 8 + 4];
            float4 b0 = *(const float4*)&b_tile[kk][tx * 4];
            float4 b1 = *(const float4*)&b_tile[kk][tx * 4 + 128];
            float av[8] = {a0.x, a0.y, a0.z, a0.w, a1.x, a1.y, a1.z, a1.w};
            float bv[8] = {b0.x, b0.y, b0.z, b0.w, b1.x, b1.y, b1.z, b1.w};
#pragma unroll
            for (int i = 0; i < 8; ++i)
#pragma unroll
                for (int jj = 0; jj < 8; ++jj) acc[i][jj] += av[i] * bv[jj];
        }
        __syncthreads();
    }

    if (e0 < DI) {
#pragma unroll
        for (int i = 0; i < 8; ++i) {
            size_t row = (size_t)t * N_SEQ + n0 + ty * 8 + i;
            *(float4*)&xc_raw[row * DI + e0 + tx * 4]       = make_float4(acc[i][0], acc[i][1], acc[i][2], acc[i][3]);
            *(float4*)&xc_raw[row * DI + e0 + tx * 4 + 128] = make_float4(acc[i][4], acc[i][5], acc[i][6], acc[i][7]);
        }
    } else {
        const int ez = e0 - DI;
#pragma unroll
        for (int i = 0; i < 8; ++i) {
            size_t row = (size_t)(n0 + ty * 8 + i);
            *(float4*)&z_raw[row * DI + ez + tx * 4]       = make_float4(acc[i][0], acc[i][1], acc[i][2], acc[i][3]);
            *(float4*)&z_raw[row * DI + ez + tx * 4 + 128] = make_float4(acc[i][4], acc[i][5], acc[i][6], acc[i][7]);
        }
    }
}

// ---------------------------------------------------------------------------
// K3: x_dbl = silu(conv(xc_raw)) @ x_proj_w^T, conv+bias+SiLU fused into the
// A-tile staging (k2 eliminated).  M=18432, N=48, K=512.
// ---------------------------------------------------------------------------
__global__ __launch_bounds__(256) void k3_xproj(const float* __restrict__ xc_raw,
                                                const float* __restrict__ conv_w,  // (512,4)
                                                const float* __restrict__ conv_b,  // (512)
                                                const float* __restrict__ w,       // (48,512)
                                                float* __restrict__ x_dbl)         // [18432][48]
{
    const int r0 = blockIdx.x * 64;        // rows share one t (64 | 1152)
    const int t  = r0 / N_SEQ;
    const int n0 = r0 - t * N_SEQ;
    const int tid = threadIdx.x;
    const int tx = tid & 15;     // col0 = tx*3
    const int ty = tid >> 4;     // row0 = ty*4

    __shared__ float a_tile[16][68];   // [k][row]
    __shared__ float b_tile[16][49];   // [k][col]

    float acc[4][3] = {};

    for (int k0 = 0; k0 < DI; k0 += 16) {
        {   // A staging with fused depthwise conv + bias + SiLU
            int rl = tid >> 2;            // 0..63
            int k4 = (tid & 3) * 4;       // 0,4,8,12
            int n  = n0 + rl;
            float4 cb4 = *(const float4*)&conv_b[k0 + k4];
            float s[4] = {cb4.x, cb4.y, cb4.z, cb4.w};
            float cwm[4][4];
#pragma unroll
            for (int i = 0; i < 4; ++i) {
                float4 cv = *(const float4*)&conv_w[(size_t)(k0 + k4 + i) * 4];
                cwm[i][0] = cv.x; cwm[i][1] = cv.y; cwm[i][2] = cv.z; cwm[i][3] = cv.w;
            }
#pragma unroll
            for (int j = 0; j < 4; ++j) {
                int tt = t - j;
                if (tt >= 0) {
                    float4 xv = *(const float4*)&xc_raw[((size_t)tt * N_SEQ + n) * DI + k0 + k4];
                    s[0] += xv.x * cwm[0][3 - j];
                    s[1] += xv.y * cwm[1][3 - j];
                    s[2] += xv.z * cwm[2][3 - j];
                    s[3] += xv.w * cwm[3][3 - j];
                }
            }
#pragma unroll
            for (int i = 0; i < 4; ++i) {
                float v = s[i];
                a_tile[k4 + i][rl] = v / (1.f + __expf(-v));
            }
        }
        if (tid < 192) {
            int cl = tid >> 2; int k4 = (tid & 3) * 4;
            float4 v = *(const float4*)&w[(size_t)cl * DI + k0 + k4];
            b_tile[k4 + 0][cl] = v.x; b_tile[k4 + 1][cl] = v.y;
            b_tile[k4 + 2][cl] = v.z; b_tile[k4 + 3][cl] = v.w;
        }
        __syncthreads();
#pragma unroll
        for (int kk = 0; kk < 16; ++kk) {
            float4 a = *(const float4*)&a_tile[kk][ty * 4];
            float b0 = b_tile[kk][tx * 3 + 0];
            float b1 = b_tile[kk][tx * 3 + 1];
            float b2 = b_tile[kk][tx * 3 + 2];
            acc[0][0] += a.x * b0; acc[0][1] += a.x * b1; acc[0][2] += a.x * b2;
            acc[1][0] += a.y * b0; acc[1][1] += a.y * b1; acc[1][2] += a.y * b2;
            acc[2][0] += a.z * b0; acc[2][1] += a.z * b1; acc[2][2] += a.z * b2;
            acc[3][0] += a.w * b0; acc[3][1] += a.w * b1; acc[3][2] += a.w * b2;
        }
        __syncthreads();
    }
#pragma unroll
    for (int i = 0; i < 4; ++i)
#pragma unroll
        for (int c = 0; c < 3; ++c)
            x_dbl[(size_t)(r0 + ty * 4 + i) * 48 + tx * 3 + c] = acc[i][c];
}

// ---------------------------------------------------------------------------
// K4: fused conv+SiLU (staging) + dt_proj + softplus + selective scan +
// D-residual + silu(z) gate.  One block (512 threads) per sequence.
// ---------------------------------------------------------------------------
__global__ __launch_bounds__(512) void k4_scan(const float* __restrict__ xc_raw,  // [16][1152][512]
                                               const float* __restrict__ conv_w,  // (512,4)
                                               const float* __restrict__ conv_b,  // (512)
                                               const float* __restrict__ x_dbl,   // [16*1152][48]
                                               const float* __restrict__ dtw,     // (512,16)
                                               const float* __restrict__ dtb,     // (512)
                                               const float* __restrict__ A_log,   // (512,16)
                                               const float* __restrict__ Dp,      // (512)
                                               const float* __restrict__ z_raw,   // [1152][512]
                                               float* __restrict__ y_out)         // [1152][512]
{
    const int n = blockIdx.x;
    const int tid = threadIdx.x;   // channel d == e (DI == 512 == blockDim)

    __shared__ float xs[T_LEN * DI];   // 32 KB, silu(conv(xc_raw))
    __shared__ float xd[T_LEN * 48];   // 3 KB

    {   // fused depthwise conv + bias + SiLU while staging
        float4 cwv = *(const float4*)&conv_w[(size_t)tid * 4];
        float cwa[4] = {cwv.x, cwv.y, cwv.z, cwv.w};
        float cbv = conv_b[tid];
#pragma unroll
        for (int t = 0; t < T_LEN; ++t) {
            float s = cbv;
#pragma unroll
            for (int j = 0; j < 4; ++j) {
                int tt = t - j;
                if (tt >= 0) s += xc_raw[((size_t)tt * N_SEQ + n) * DI + tid] * cwa[3 - j];
            }
            xs[t * DI + tid] = s / (1.f + __expf(-s));
        }
    }
    for (int i = tid; i < T_LEN * 48; i += 512) {
        int t = i / 48; int r = i - t * 48;
        xd[i] = x_dbl[((size_t)t * N_SEQ + n) * 48 + r];
    }

    float wreg[16], areg[16], h[16];
#pragma unroll
    for (int r = 0; r < 16; ++r) wreg[r] = dtw[tid * 16 + r];
#pragma unroll
    for (int s = 0; s < 16; ++s) { areg[s] = -__expf(A_log[tid * 16 + s]); h[s] = 0.f; }
    const float bias = dtb[tid];
    __syncthreads();

    for (int t = 0; t < T_LEN; ++t) {
        float dv = bias;
#pragma unroll
        for (int r = 0; r < 16; ++r) dv += xd[t * 48 + r] * wreg[r];
        float dt = fmaxf(dv, 0.f) + log1pf(__expf(-fabsf(dv)));   // softplus
        float dtx = dt * xs[t * DI + tid];
#pragma unroll
        for (int s = 0; s < 16; ++s) {
            float dA = __expf(dt * areg[s]);
            h[s] = dA * h[s] + dtx * xd[t * 48 + 16 + s];
        }
    }

    float y = 0.f;
#pragma unroll
    for (int s = 0; s < 16; ++s) y += h[s] * xd[15 * 48 + 32 + s];
    y += xs[15 * DI + tid] * Dp[tid];
    float z = z_raw[(size_t)n * DI + tid];
    y *= z / (1.f + __expf(-z));
    y_out[(size_t)n * DI + tid] = y;
}

// ---------------------------------------------------------------------------
// K5: out = y_out @ out_proj_w^T, scattered to (B,C,H,W).
// ---------------------------------------------------------------------------
__global__ __launch_bounds__(256) void k5_outproj(const float* __restrict__ y_in,  // [1152][512]
                                                  const float* __restrict__ w,     // (256,512)
                                                  float* __restrict__ out)         // (2,256,24,24)
{
    const int c0 = blockIdx.x * 64;
    const int n0 = blockIdx.y * 64;
    const int tid = threadIdx.x;
    const int tx = tid & 15, ty = tid >> 4;

    __shared__ float wt[16][68];   // [k][c]
    __shared__ float yt[16][68];   // [k][n]

    float acc[4][4] = {};  // [c][n]

    for (int k0 = 0; k0 < DI; k0 += 16) {
        {   int l = tid >> 2; int k4 = (tid & 3) * 4;
            float4 v = *(const float4*)&w[(size_t)(c0 + l) * DI + k0 + k4];
            wt[k4 + 0][l] = v.x; wt[k4 + 1][l] = v.y; wt[k4 + 2][l] = v.z; wt[k4 + 3][l] = v.w;
            float4 u = *(const float4*)&y_in[(size_t)(n0 + l) * DI + k0 + k4];
            yt[k4 + 0][l] = u.x; yt[k4 + 1][l] = u.y; yt[k4 + 2][l] = u.z; yt[k4 + 3][l] = u.w; }
        __syncthreads();
#pragma unroll
        for (int kk = 0; kk < 16; ++kk) {
            float4 a = *(const float4*)&wt[kk][ty * 4];
            float4 bb = *(const float4*)&yt[kk][tx * 4];
            acc[0][0] += a.x * bb.x; acc[0][1] += a.x * bb.y; acc[0][2] += a.x * bb.z; acc[0][3] += a.x * bb.w;
            acc[1][0] += a.y * bb.x; acc[1][1] += a.y * bb.y; acc[1][2] += a.y * bb.z; acc[1][3] += a.y * bb.w;
            acc[2][0] += a.z * bb.x; acc[2][1] += a.z * bb.y; acc[2][2] += a.z * bb.z; acc[2][3] += a.z * bb.w;
            acc[3][0] += a.w * bb.x; acc[3][1] += a.w * bb.y; acc[3][2] += a.w * bb.z; acc[3][3] += a.w * bb.w;
        }
        __syncthreads();
    }

    const int b = n0 / HWSZ;
    const int hwb = n0 - b * HWSZ + tx * 4;
#pragma unroll
    for (int i = 0; i < 4; ++i) {
        float4 v = make_float4(acc[i][0], acc[i][1], acc[i][2], acc[i][3]);
        *(float4*)&out[(size_t)b * (DM * HWSZ) + (size_t)(c0 + ty * 4 + i) * HWSZ + hwb] = v;
    }
}

// ---------------------------------------------------------------------------
extern "C" void kernel_launch(void* const* d_in, const int* in_sizes, int n_in,
                              void* d_out, int out_size, void* d_ws, size_t ws_size,
                              hipStream_t stream) {
    const float* x_seq     = (const float*)d_in[0];
    const float* in_proj_w = (const float*)d_in[1];
    const float* conv_w    = (const float*)d_in[2];
    const float* conv_b    = (const float*)d_in[3];
    const float* x_proj_w  = (const float*)d_in[4];
    const float* dt_proj_w = (const float*)d_in[5];
    const float* dt_proj_b = (const float*)d_in[6];
    const float* A_log     = (const float*)d_in[7];
    const float* Dp        = (const float*)d_in[8];
    const float* out_proj_w= (const float*)d_in[9];
    float* out = (float*)d_out;
    float* ws  = (float*)d_ws;

    const size_t S1 = (size_t)T_LEN * N_SEQ * DI;     // 9.4M floats
    float* xc_raw = ws;
    float* z_raw  = ws + S1;
    float* x_dbl  = z_raw + (size_t)N_SEQ * DI;
    float* y_out  = x_dbl + (size_t)T_LEN * N_SEQ * 48;

    k1_inproj<<<dim3(18, 4, 16), 256, 0, stream>>>(x_seq, in_proj_w, xc_raw, z_raw);
    k3_xproj <<<288, 256, 0, stream>>>(xc_raw, conv_w, conv_b, x_proj_w, x_dbl);
    k4_scan  <<<1152, 512, 0, stream>>>(xc_raw, conv_w, conv_b, x_dbl, dt_proj_w, dt_proj_b,
                                        A_log, Dp, z_raw, y_out);
    k5_outproj<<<dim3(4, 18), 256, 0, stream>>>(y_out, out_proj_w, out);
}